// Round 4
// baseline (252.074 us; speedup 1.0000x reference)
//
#include <hip/hip_runtime.h>

typedef _Float16 h8 __attribute__((ext_vector_type(8)));
typedef _Float16 h4 __attribute__((ext_vector_type(4)));
typedef float f4 __attribute__((ext_vector_type(4)));

constexpr int NB = 64;     // batch
constexpr int NI = 2048;   // input capsules
constexpr int NQ = 16;     // input dim
constexpr int NJ = 32;     // num capsules
constexpr int NP = 32;     // dim capsule
constexpr int VSZ = NB * NJ * NP;   // 65536 per v-buffer

// ---------------------------------------------------------------------------
// MFMA plan, per (j,i) task:  D[p(32), b(64)] = sum_q W[j,i,p,q] * x[b,i,q]
//   v_mfma_f32_16x16x32_f16, A = W-side [M=p16, K=32], B = x-side [K=32, N=b16]
//   K slots: k<16 -> (W_hi[q=k], x[q=k]) ; k>=16 -> (W_lo[q=k-16], x[q=k-16])
//   => D = sum_q (W_hi + W_lo) * x : W at ~f32 precision, x at f16 (2^-11)
//   A lane layout: row p = l&15 (+16 per pfrag), k = (l>>4)*8+e
//   B lane layout: col b = l&15 (+16 per bfrag), k = (l>>4)*8+e  (halves dup'd)
//   D lane layout: col b = l&15, row p = (l>>4)*4 + reg (+16 per pfrag)
// ---------------------------------------------------------------------------

__global__ __launch_bounds__(256)
void zero_kernel(f4* __restrict__ p)
{
    const f4 z = {0.f, 0.f, 0.f, 0.f};
    p[(size_t)blockIdx.x * 256 + threadIdx.x] = z;
}

// x fragment prepack: xp[(i*4+bf)*64 + lane] = 8 f16 of x[b=(l&15)+16bf, i, q0..q0+7]
__global__ __launch_bounds__(256)
void xpack_kernel(const float* __restrict__ X, h8* __restrict__ xp)
{
    const int i = blockIdx.x;
    const int t = threadIdx.x;
    const int bf = t >> 6, l = t & 63;
    const int b = (l & 15) + 16 * bf;
    const int q0 = ((l >> 4) & 1) * 8;
    const float* xs = X + ((size_t)b * NI + i) * NQ + q0;
    const float4 u = *reinterpret_cast<const float4*>(xs);
    const float4 v = *reinterpret_cast<const float4*>(xs + 4);
    h8 h;
    h[0] = (_Float16)u.x; h[1] = (_Float16)u.y; h[2] = (_Float16)u.z; h[3] = (_Float16)u.w;
    h[4] = (_Float16)v.x; h[5] = (_Float16)v.y; h[6] = (_Float16)v.z; h[7] = (_Float16)v.w;
    xp[(size_t)(i * 4 + bf) * 64 + l] = h;
}

// Build one A fragment: 8 f32 W -> f16 hi (lanes 0..31) or f16 residual (lanes 32..63)
__device__ inline h8 buildA(const float* __restrict__ wp, bool lo)
{
    const float4 u = *reinterpret_cast<const float4*>(wp);
    const float4 v = *reinterpret_cast<const float4*>(wp + 4);
    float wv_[8] = {u.x, u.y, u.z, u.w, v.x, v.y, v.z, v.w};
    h8 a;
#pragma unroll
    for (int e = 0; e < 8; ++e) {
        const float w = wv_[e];
        const _Float16 hi = (_Float16)w;
        const float r = w - (float)hi;
        a[e] = lo ? (_Float16)r : hi;
    }
    return a;
}

// squash scale factor for squared-norm s2
__device__ inline float sqscale(float s2)
{
    return s2 / ((1.f + s2) * sqrtf(s2 + 1e-7f));
}

// K1: logits + softmax -> routing coefficients c (f16), with squash fused:
//   SMODE 0: S = squash(U1/32)           (U1 = raw uniform accumulation)
//   SMODE 1: S = squash(U1/32) + squash(U2)
// block = i-chunk of 8, all 32 j, all 64 b. 8 waves; wave wv owns j = wv*4..+3.
template <int SMODE>
__global__ __launch_bounds__(512)
void logits_kernel(const float* __restrict__ Wg, const h8* __restrict__ xp,
                   const float* __restrict__ U1, const float* __restrict__ U2,
                   _Float16* __restrict__ cp)
{
    __shared__ float L[8][32][64];   // 64 KB logits
    const int t = threadIdx.x, wv = t >> 6, l = t & 63;
    const int i0 = blockIdx.x * 8;
    const bool lo = l >= 32;
    const int q0 = ((l >> 4) & 1) * 8;

#pragma unroll 1
    for (int jj = 0; jj < 4; ++jj) {
        const int j = wv * 4 + jj;

        // ---- build S[b,j,p] fragments in-register (fused squash) ----
        float sreg[4][8];
#pragma unroll
        for (int bf = 0; bf < 4; ++bf) {
            const int b = (l & 15) + 16 * bf;
            const size_t base = ((size_t)b * NJ + j) * NP + (l >> 4) * 4;
            float va[8];
#pragma unroll
            for (int pf = 0; pf < 2; ++pf) {
                const f4 u = *reinterpret_cast<const f4*>(U1 + base + 16 * pf);
#pragma unroll
                for (int r = 0; r < 4; ++r) va[pf * 4 + r] = u[r] * (1.f / 32.f);
            }
            float s2 = 0.f;
#pragma unroll
            for (int e = 0; e < 8; ++e) s2 += va[e] * va[e];
            s2 += __shfl_xor(s2, 16);
            s2 += __shfl_xor(s2, 32);
            const float sc1 = sqscale(s2);
#pragma unroll
            for (int e = 0; e < 8; ++e) sreg[bf][e] = va[e] * sc1;

            if (SMODE == 1) {
                float vb[8];
#pragma unroll
                for (int pf = 0; pf < 2; ++pf) {
                    const f4 u = *reinterpret_cast<const f4*>(U2 + base + 16 * pf);
#pragma unroll
                    for (int r = 0; r < 4; ++r) vb[pf * 4 + r] = u[r];
                }
                float t2 = 0.f;
#pragma unroll
                for (int e = 0; e < 8; ++e) t2 += vb[e] * vb[e];
                t2 += __shfl_xor(t2, 16);
                t2 += __shfl_xor(t2, 32);
                const float sc2 = sqscale(t2);
#pragma unroll
                for (int e = 0; e < 8; ++e) sreg[bf][e] += vb[e] * sc2;
            }
        }

#pragma unroll 2
        for (int ii = 0; ii < 8; ++ii) {
            const int i = i0 + ii;
            const float* wbase = Wg + ((size_t)j * NI + i) * (NP * NQ) + q0;
            const h8 A0 = buildA(wbase + (size_t)(l & 15) * NQ, lo);
            const h8 A1 = buildA(wbase + (size_t)((l & 15) + 16) * NQ, lo);
            const h8* xpb = xp + (size_t)i * 4 * 64;
            f4 D[2][4];
#pragma unroll
            for (int pf = 0; pf < 2; ++pf)
#pragma unroll
                for (int bf = 0; bf < 4; ++bf) { f4 Z = {0.f, 0.f, 0.f, 0.f}; D[pf][bf] = Z; }
#pragma unroll
            for (int bf = 0; bf < 4; ++bf) {
                const h8 B = xpb[bf * 64 + l];
                D[0][bf] = __builtin_amdgcn_mfma_f32_16x16x32_f16(A0, B, D[0][bf], 0, 0, 0);
                D[1][bf] = __builtin_amdgcn_mfma_f32_16x16x32_f16(A1, B, D[1][bf], 0, 0, 0);
            }
            // logit[b] = sum_p S[b,j,p] * hat[p,b]
            float part[4];
#pragma unroll
            for (int bf = 0; bf < 4; ++bf) {
                float p_ = 0.f;
#pragma unroll
                for (int pf = 0; pf < 2; ++pf)
#pragma unroll
                    for (int r = 0; r < 4; ++r) p_ += sreg[bf][pf * 4 + r] * D[pf][bf][r];
                p_ += __shfl_xor(p_, 16);
                p_ += __shfl_xor(p_, 32);
                part[bf] = p_;
            }
            const int hb = l >> 4;
            const float wval = hb == 0 ? part[0] : hb == 1 ? part[1] : hb == 2 ? part[2] : part[3];
            L[ii][j][(l & 15) + 16 * hb] = wval;
        }
    }
    __syncthreads();

    // softmax over j, one thread per (b, ii); write c in accum's B-frag order
    {
        const int b = t & 63, ii = t >> 6;
        const int i = i0 + ii;
        float lv[32];
        float m = -1e30f;
#pragma unroll
        for (int j = 0; j < 32; ++j) { lv[j] = L[ii][j][b]; m = fmaxf(m, lv[j]); }
        float s = 0.f;
#pragma unroll
        for (int j = 0; j < 32; ++j) { lv[j] = __expf(lv[j] - m); s += lv[j]; }
        const float inv = 1.f / s;
#pragma unroll
        for (int j = 0; j < 32; ++j)
            cp[((size_t)j * NI + i) * 64 + (b & 15) * 4 + (b >> 4)] = (_Float16)(lv[j] * inv);
    }
}

// K2: ACC[b,j,p] += sum_i c[b,j,i] * hat[b,j,i,p]  (HASC=false -> uniform c)
// block = (j, i-stripe of 128); wave wv accumulates its 16 i's in D regs.
template <bool HASC>
__global__ __launch_bounds__(512)
void accum_kernel(const float* __restrict__ Wg, const h8* __restrict__ xp,
                  const _Float16* __restrict__ cp, float* __restrict__ ACC)
{
    const int t = threadIdx.x, wv = t >> 6, l = t & 63;
    const int j = blockIdx.x >> 4, is = blockIdx.x & 15;
    const bool lo = l >= 32;
    const int q0 = ((l >> 4) & 1) * 8;

    f4 D[2][4];
#pragma unroll
    for (int pf = 0; pf < 2; ++pf)
#pragma unroll
        for (int bf = 0; bf < 4; ++bf) { f4 Z = {0.f, 0.f, 0.f, 0.f}; D[pf][bf] = Z; }

    const int ibase = is * 128 + wv * 16;
#pragma unroll 2
    for (int ii = 0; ii < 16; ++ii) {
        const int i = ibase + ii;
        const float* wbase = Wg + ((size_t)j * NI + i) * (NP * NQ) + q0;
        const h8 A0 = buildA(wbase + (size_t)(l & 15) * NQ, lo);
        const h8 A1 = buildA(wbase + (size_t)((l & 15) + 16) * NQ, lo);
        const h8* xpb = xp + (size_t)i * 4 * 64;
        h4 c4;
        if (HASC)
            c4 = *reinterpret_cast<const h4*>(cp + ((size_t)j * NI + i) * 64 + (l & 15) * 4);
#pragma unroll
        for (int bf = 0; bf < 4; ++bf) {
            h8 B = xpb[bf * 64 + l];
            if (HASC) B = B * c4[bf];   // fold c into B operand (v_pk_mul_f16)
            D[0][bf] = __builtin_amdgcn_mfma_f32_16x16x32_f16(A0, B, D[0][bf], 0, 0, 0);
            D[1][bf] = __builtin_amdgcn_mfma_f32_16x16x32_f16(A1, B, D[1][bf], 0, 0, 0);
        }
    }

    // cross-wave reduce in LDS, then one atomic per (b,p)
    __shared__ float R[8][64 * 36];   // stride 36 keeps f4 stores 16B-aligned
#pragma unroll
    for (int pf = 0; pf < 2; ++pf)
#pragma unroll
        for (int bf = 0; bf < 4; ++bf) {
            const int b = (l & 15) + 16 * bf, p = (l >> 4) * 4 + 16 * pf;
            *reinterpret_cast<f4*>(&R[wv][b * 36 + p]) = D[pf][bf];
        }
    __syncthreads();
#pragma unroll
    for (int k = 0; k < 4; ++k) {
        const int id = t + k * 512;
        const int b = id >> 5, p = id & 31;
        float s = 0.f;
#pragma unroll
        for (int w8 = 0; w8 < 8; ++w8) s += R[w8][b * 36 + p];
        atomicAdd(ACC + ((size_t)b * NJ + j) * NP + p, s);
    }
}

// out = squash(U) over last axis (P=32)
__global__ __launch_bounds__(256)
void squash_kernel(const float* __restrict__ U, float* __restrict__ OUT)
{
    const int t   = threadIdx.x;
    const int row = blockIdx.x * 8 + (t >> 5);
    const int p   = t & 31;
    const float val = U[row * 32 + p];
    float sq = val * val;
#pragma unroll
    for (int d = 1; d < 32; d <<= 1) sq += __shfl_xor(sq, d);
    OUT[row * 32 + p] = val * sqscale(sq);
}

extern "C" void kernel_launch(void* const* d_in, const int* in_sizes, int n_in,
                              void* d_out, int out_size, void* d_ws, size_t ws_size,
                              hipStream_t stream)
{
    const float* X  = (const float*)d_in[0];   // [64, 2048, 16]
    const float* Wg = (const float*)d_in[1];   // [32, 2048, 32, 16]
    float* out = (float*)d_out;                // [64, 32, 32]

    // workspace: v1u, v2u, ou (contiguous, zeroed) | xp | cp
    float* v1u = (float*)d_ws;
    float* v2u = v1u + VSZ;
    float* ou  = v2u + VSZ;
    h8* xp = (h8*)((char*)d_ws + (size_t)3 * VSZ * 4);                 // 8 MB
    _Float16* cp = (_Float16*)((char*)xp + (size_t)NI * 4 * 64 * 16);  // 8 MB

    xpack_kernel<<<NI, 256, 0, stream>>>(X, xp);
    zero_kernel<<<3 * VSZ * 4 / (256 * 16), 256, 0, stream>>>((f4*)d_ws);

    // pass A: c = 1/32 uniform -> v1u
    accum_kernel<false><<<512, 512, 0, stream>>>(Wg, xp, nullptr, v1u);

    // pass B: S = squash(v1u/32); logits+softmax -> cp; weighted accum -> v2u
    logits_kernel<0><<<NI / 8, 512, 0, stream>>>(Wg, xp, v1u, nullptr, cp);
    accum_kernel<true><<<512, 512, 0, stream>>>(Wg, xp, cp, v2u);

    // pass C: S = squash(v1u/32) + squash(v2u); logits -> cp; accum -> ou
    logits_kernel<1><<<NI / 8, 512, 0, stream>>>(Wg, xp, v1u, v2u, cp);
    accum_kernel<true><<<512, 512, 0, stream>>>(Wg, xp, cp, ou);

    squash_kernel<<<VSZ / 256, 256, 0, stream>>>(ou, out);
}

// Round 5
// 207.012 us; speedup vs baseline: 1.2177x; 1.2177x over previous
//
#include <hip/hip_runtime.h>

typedef _Float16 h8 __attribute__((ext_vector_type(8)));
typedef _Float16 h4 __attribute__((ext_vector_type(4)));
typedef float f4 __attribute__((ext_vector_type(4)));

constexpr int NB = 64;     // batch
constexpr int NI = 2048;   // input capsules
constexpr int NQ = 16;     // input dim
constexpr int NJ = 32;     // num capsules
constexpr int NP = 32;     // dim capsule
constexpr int VSZ = NB * NJ * NP;   // 65536 per v-buffer

// ---------------------------------------------------------------------------
// MFMA plan, per (j,i) task:  D[p(32), b(64)] = sum_q W[j,i,p,q] * x[b,i,q]
//   v_mfma_f32_16x16x32_f16, A = W-side [M=p16, K=32], B = x-side [K=32, N=b16]
//   K slots: k<16 -> (W_hi[q=k], x[q=k]) ; k>=16 -> (W_lo[q=k-16], x[q=k-16])
//   => D = sum_q (W_hi + W_lo) * x : W at ~f32 precision, x at f16 (2^-11)
//   A lane layout: row p = l&15 (+16 per pfrag), k = (l>>4)*8+e
//   B lane layout: col b = l&15 (+16 per bfrag), k = (l>>4)*8+e  (halves dup'd)
//   D lane layout: col b = l&15, row p = (l>>4)*4 + reg (+16 per pfrag)
// W is prepacked ONCE into this fragment layout (wpack) so the 5 hat passes
// do zero per-element conversion VALU work.
// ---------------------------------------------------------------------------

__global__ __launch_bounds__(256)
void zero_kernel(f4* __restrict__ p)
{
    const f4 z = {0.f, 0.f, 0.f, 0.f};
    p[(size_t)blockIdx.x * 256 + threadIdx.x] = z;
}

// x fragment prepack: xp[(i*4+bf)*64 + lane] = 8 f16 of x[b=(l&15)+16bf, i, q0..q0+7]
__global__ __launch_bounds__(256)
void xpack_kernel(const float* __restrict__ X, h8* __restrict__ xp)
{
    const int i = blockIdx.x;
    const int t = threadIdx.x;
    const int bf = t >> 6, l = t & 63;
    const int b = (l & 15) + 16 * bf;
    const int q0 = ((l >> 4) & 1) * 8;
    const float* xs = X + ((size_t)b * NI + i) * NQ + q0;
    const float4 u = *reinterpret_cast<const float4*>(xs);
    const float4 v = *reinterpret_cast<const float4*>(xs + 4);
    h8 h;
    h[0] = (_Float16)u.x; h[1] = (_Float16)u.y; h[2] = (_Float16)u.z; h[3] = (_Float16)u.w;
    h[4] = (_Float16)v.x; h[5] = (_Float16)v.y; h[6] = (_Float16)v.z; h[7] = (_Float16)v.w;
    xp[(size_t)(i * 4 + bf) * 64 + l] = h;
}

// W fragment prepack: wp[((j*NI+i)*2 + frag)*64 + lane] = A-fragment h8.
// lane<32 holds f16(W) (k<16), lane>=32 holds f16 residual (k>=16).
__global__ __launch_bounds__(256)
void wpack_kernel(const float* __restrict__ Wg, h8* __restrict__ wp)
{
    const size_t g = (size_t)blockIdx.x * 256 + threadIdx.x;  // = (pair*2+frag)*64 + l
    const int l = (int)(g & 63);
    const size_t pfrag = g >> 6;          // pair*2 + frag
    const int frag = (int)(pfrag & 1);
    const size_t pair = pfrag >> 1;       // j*NI + i
    const int p = (l & 15) + 16 * frag;
    const int q0 = ((l >> 4) & 1) * 8;
    const float* src = Wg + (pair * NP + p) * NQ + q0;
    const float4 u = *reinterpret_cast<const float4*>(src);
    const float4 v = *reinterpret_cast<const float4*>(src + 4);
    float wv_[8] = {u.x, u.y, u.z, u.w, v.x, v.y, v.z, v.w};
    h8 a;
    if (l < 32) {
#pragma unroll
        for (int e = 0; e < 8; ++e) a[e] = (_Float16)wv_[e];
    } else {
#pragma unroll
        for (int e = 0; e < 8; ++e) {
            const _Float16 hi = (_Float16)wv_[e];
            a[e] = (_Float16)(wv_[e] - (float)hi);
        }
    }
    wp[g] = a;
}

// squash scale factor for squared-norm s2
__device__ inline float sqscale(float s2)
{
    return s2 / ((1.f + s2) * sqrtf(s2 + 1e-7f));
}

// K1: logits + softmax -> routing coefficients c (f16), with squash fused:
//   SMODE 0: S = squash(U1/32) ;  SMODE 1: S = squash(U1/32) + squash(U2)
// block = i-chunk of 8, all 32 j, all 64 b. 8 waves; wave wv owns j = wv*4..+3.
template <int SMODE>
__global__ __launch_bounds__(512)
void logits_kernel(const h8* __restrict__ wp, const h8* __restrict__ xp,
                   const float* __restrict__ U1, const float* __restrict__ U2,
                   _Float16* __restrict__ cp)
{
    __shared__ float L[8][32][64];   // 64 KB logits (reused for c)
    const int t = threadIdx.x, wv = t >> 6, l = t & 63;
    const int i0 = blockIdx.x * 8;

#pragma unroll 1
    for (int jj = 0; jj < 4; ++jj) {
        const int j = wv * 4 + jj;

        // ---- build S[b,j,p] fragments in-register (fused squash) ----
        float sreg[4][8];
#pragma unroll
        for (int bf = 0; bf < 4; ++bf) {
            const int b = (l & 15) + 16 * bf;
            const size_t base = ((size_t)b * NJ + j) * NP + (l >> 4) * 4;
            float va[8];
#pragma unroll
            for (int pf = 0; pf < 2; ++pf) {
                const f4 u = *reinterpret_cast<const f4*>(U1 + base + 16 * pf);
#pragma unroll
                for (int r = 0; r < 4; ++r) va[pf * 4 + r] = u[r] * (1.f / 32.f);
            }
            float s2 = 0.f;
#pragma unroll
            for (int e = 0; e < 8; ++e) s2 += va[e] * va[e];
            s2 += __shfl_xor(s2, 16);
            s2 += __shfl_xor(s2, 32);
            const float sc1 = sqscale(s2);
#pragma unroll
            for (int e = 0; e < 8; ++e) sreg[bf][e] = va[e] * sc1;

            if (SMODE == 1) {
                float vb[8];
#pragma unroll
                for (int pf = 0; pf < 2; ++pf) {
                    const f4 u = *reinterpret_cast<const f4*>(U2 + base + 16 * pf);
#pragma unroll
                    for (int r = 0; r < 4; ++r) vb[pf * 4 + r] = u[r];
                }
                float t2 = 0.f;
#pragma unroll
                for (int e = 0; e < 8; ++e) t2 += vb[e] * vb[e];
                t2 += __shfl_xor(t2, 16);
                t2 += __shfl_xor(t2, 32);
                const float sc2 = sqscale(t2);
#pragma unroll
                for (int e = 0; e < 8; ++e) sreg[bf][e] += vb[e] * sc2;
            }
        }

#pragma unroll 1
        for (int ii = 0; ii < 8; ++ii) {
            const int i = i0 + ii;
            const h8* wpji = wp + ((size_t)j * NI + i) * 2 * 64 + l;
            const h8 A0 = wpji[0];
            const h8 A1 = wpji[64];
            const h8* xpb = xp + (size_t)i * 4 * 64;
            f4 D[2][4];
#pragma unroll
            for (int pf = 0; pf < 2; ++pf)
#pragma unroll
                for (int bf = 0; bf < 4; ++bf) { f4 Z = {0.f, 0.f, 0.f, 0.f}; D[pf][bf] = Z; }
#pragma unroll
            for (int bf = 0; bf < 4; ++bf) {
                const h8 B = xpb[bf * 64 + l];
                D[0][bf] = __builtin_amdgcn_mfma_f32_16x16x32_f16(A0, B, D[0][bf], 0, 0, 0);
                D[1][bf] = __builtin_amdgcn_mfma_f32_16x16x32_f16(A1, B, D[1][bf], 0, 0, 0);
            }
            // logit[b] = sum_p S[b,j,p] * hat[p,b]
            float part[4];
#pragma unroll
            for (int bf = 0; bf < 4; ++bf) {
                float p_ = 0.f;
#pragma unroll
                for (int pf = 0; pf < 2; ++pf)
#pragma unroll
                    for (int r = 0; r < 4; ++r) p_ += sreg[bf][pf * 4 + r] * D[pf][bf][r];
                p_ += __shfl_xor(p_, 16);
                p_ += __shfl_xor(p_, 32);
                part[bf] = p_;
            }
            const int hb = l >> 4;
            const float wval = hb == 0 ? part[0] : hb == 1 ? part[1] : hb == 2 ? part[2] : part[3];
            L[ii][j][(l & 15) + 16 * hb] = wval;
        }
    }
    __syncthreads();

    // softmax over j, one thread per (b, ii); write c back into L
    {
        const int b = t & 63, ii = t >> 6;
        float lv[32];
        float m = -1e30f;
#pragma unroll
        for (int j = 0; j < 32; ++j) { lv[j] = L[ii][j][b]; m = fmaxf(m, lv[j]); }
        float s = 0.f;
#pragma unroll
        for (int j = 0; j < 32; ++j) { lv[j] = __expf(lv[j] - m); s += lv[j]; }
        const float inv = 1.f / s;
#pragma unroll
        for (int j = 0; j < 32; ++j) L[ii][j][b] = lv[j] * inv;
    }
    __syncthreads();

    // cooperative coalesced cp write: per (j,i) a contiguous 128 B chunk,
    // element order = accum's h4 read order: pos r*4+e holds c[b=16e+r]
    {
        const int jw = t >> 4, r = t & 15;
#pragma unroll 1
        for (int ii = 0; ii < 8; ++ii) {
            h4 c4;
#pragma unroll
            for (int e = 0; e < 4; ++e) c4[e] = (_Float16)L[ii][jw][16 * e + r];
            *reinterpret_cast<h4*>(cp + ((size_t)jw * NI + i0 + ii) * 64 + r * 4) = c4;
        }
    }
}

// K2: ACC[b,j,p] += sum_i c[b,j,i] * hat[b,j,i,p]  (HASC=false -> uniform c)
// block = (j, i-stripe of 128); wave wv accumulates its 16 i's in D regs.
template <bool HASC>
__global__ __launch_bounds__(512)
void accum_kernel(const h8* __restrict__ wp, const h8* __restrict__ xp,
                  const _Float16* __restrict__ cp, float* __restrict__ ACC)
{
    const int t = threadIdx.x, wv = t >> 6, l = t & 63;
    const int j = blockIdx.x >> 4, is = blockIdx.x & 15;

    f4 D[2][4];
#pragma unroll
    for (int pf = 0; pf < 2; ++pf)
#pragma unroll
        for (int bf = 0; bf < 4; ++bf) { f4 Z = {0.f, 0.f, 0.f, 0.f}; D[pf][bf] = Z; }

    const int ibase = is * 128 + wv * 16;
#pragma unroll 1
    for (int ii = 0; ii < 16; ++ii) {
        const int i = ibase + ii;
        const h8* wpji = wp + ((size_t)j * NI + i) * 2 * 64 + l;
        const h8 A0 = wpji[0];
        const h8 A1 = wpji[64];
        const h8* xpb = xp + (size_t)i * 4 * 64;
        h4 c4;
        if (HASC)
            c4 = *reinterpret_cast<const h4*>(cp + ((size_t)j * NI + i) * 64 + (l & 15) * 4);
#pragma unroll
        for (int bf = 0; bf < 4; ++bf) {
            h8 B = xpb[bf * 64 + l];
            if (HASC) B = B * c4[bf];   // fold c into B operand (v_pk_mul_f16)
            D[0][bf] = __builtin_amdgcn_mfma_f32_16x16x32_f16(A0, B, D[0][bf], 0, 0, 0);
            D[1][bf] = __builtin_amdgcn_mfma_f32_16x16x32_f16(A1, B, D[1][bf], 0, 0, 0);
        }
    }

    // cross-wave reduce in LDS, then one atomic per (b,p)
    __shared__ float R[8][64 * 36];   // stride 36 keeps f4 stores 16B-aligned
#pragma unroll
    for (int pf = 0; pf < 2; ++pf)
#pragma unroll
        for (int bf = 0; bf < 4; ++bf) {
            const int b = (l & 15) + 16 * bf, p = (l >> 4) * 4 + 16 * pf;
            *reinterpret_cast<f4*>(&R[wv][b * 36 + p]) = D[pf][bf];
        }
    __syncthreads();
#pragma unroll
    for (int k = 0; k < 4; ++k) {
        const int id = t + k * 512;
        const int b = id >> 5, p = id & 31;
        float s = 0.f;
#pragma unroll
        for (int w8 = 0; w8 < 8; ++w8) s += R[w8][b * 36 + p];
        atomicAdd(ACC + ((size_t)b * NJ + j) * NP + p, s);
    }
}

// out = squash(U) over last axis (P=32)
__global__ __launch_bounds__(256)
void squash_kernel(const float* __restrict__ U, float* __restrict__ OUT)
{
    const int t   = threadIdx.x;
    const int row = blockIdx.x * 8 + (t >> 5);
    const int p   = t & 31;
    const float val = U[row * 32 + p];
    float sq = val * val;
#pragma unroll
    for (int d = 1; d < 32; d <<= 1) sq += __shfl_xor(sq, d);
    OUT[row * 32 + p] = val * sqscale(sq);
}

extern "C" void kernel_launch(void* const* d_in, const int* in_sizes, int n_in,
                              void* d_out, int out_size, void* d_ws, size_t ws_size,
                              hipStream_t stream)
{
    const float* X  = (const float*)d_in[0];   // [64, 2048, 16]
    const float* Wg = (const float*)d_in[1];   // [32, 2048, 32, 16]
    float* out = (float*)d_out;                // [64, 32, 32]

    // workspace: v1u,v2u,ou (768 KB, zeroed) | xp 8 MB | cp 8 MB | wp 128 MB
    float* v1u = (float*)d_ws;
    float* v2u = v1u + VSZ;
    float* ou  = v2u + VSZ;
    h8* xp = (h8*)((char*)d_ws + (size_t)3 * VSZ * 4);
    _Float16* cp = (_Float16*)((char*)xp + (size_t)NI * 4 * 64 * 16);
    h8* wpk = (h8*)((char*)cp + (size_t)NJ * NI * 64 * 2);

    xpack_kernel<<<NI, 256, 0, stream>>>(X, xp);
    wpack_kernel<<<(NJ * NI * 128) / 256, 256, 0, stream>>>(Wg, wpk);
    zero_kernel<<<3 * VSZ * 4 / (256 * 16), 256, 0, stream>>>((f4*)d_ws);

    // pass A: c = 1/32 uniform -> v1u
    accum_kernel<false><<<512, 512, 0, stream>>>(wpk, xp, nullptr, v1u);

    // pass B: S = squash(v1u/32); logits+softmax -> cp; weighted accum -> v2u
    logits_kernel<0><<<NI / 8, 512, 0, stream>>>(wpk, xp, v1u, nullptr, cp);
    accum_kernel<true><<<512, 512, 0, stream>>>(wpk, xp, cp, v2u);

    // pass C: S = squash(v1u/32) + squash(v2u); logits -> cp; accum -> ou
    logits_kernel<1><<<NI / 8, 512, 0, stream>>>(wpk, xp, v1u, v2u, cp);
    accum_kernel<true><<<512, 512, 0, stream>>>(wpk, xp, cp, ou);

    squash_kernel<<<VSZ / 256, 256, 0, stream>>>(ou, out);
}

// Round 6
// 144.987 us; speedup vs baseline: 1.7386x; 1.4278x over previous
//
#include <hip/hip_runtime.h>

typedef _Float16 h8 __attribute__((ext_vector_type(8)));
typedef _Float16 h4 __attribute__((ext_vector_type(4)));
typedef float f4 __attribute__((ext_vector_type(4)));

constexpr int NB = 64;     // batch
constexpr int NI = 2048;   // input capsules
constexpr int NQ = 16;     // input dim
constexpr int NJ = 32;     // num capsules
constexpr int NP = 32;     // dim capsule
constexpr int NIP = NI / 2;         // 1024 i-pairs
constexpr int VSZ = NB * NJ * NP;   // 65536 per v-buffer

// ---------------------------------------------------------------------------
// MFMA plan (single-f16 W, i-PAIRED K):
//   per (j, ipair): D[p16,b16] += over K=32: k<16 -> W[j,i_e,p,q=k]*x[b,i_e,q]
//                                      k>=16 -> W[j,i_o,p,q=k-16]*x[b,i_o,q]
//   A lane layout: row p=l&15 (pf frag adds +16), i = l>=32 ? i_o : i_e,
//                  q0 = ((l>>4)&1)*8, elems e -> q0+e
//   B lane layout: col b=(l&15)+16bf, same (i, q) split by lane as A
//   D lane layout: col b=l&15, row p=(l>>4)*4+reg (+16 per pf)
// accum: one MFMA covers both i's (c folded per-lane into B).
// logits: same fragments, two MFMAs with the opposite lane-half of B zeroed
//         -> separate per-i hat for the S-dot.
// ---------------------------------------------------------------------------

__global__ __launch_bounds__(256)
void zero_kernel(f4* __restrict__ p)
{
    const f4 z = {0.f, 0.f, 0.f, 0.f};
    p[(size_t)blockIdx.x * 256 + threadIdx.x] = z;
}

// x pack, paired: xp[(ip*4+bf)*64 + l] = x[b=(l&15)+16bf, i=2ip+(l>=32), q0..q0+7]
__global__ __launch_bounds__(256)
void xpack_kernel(const float* __restrict__ X, h8* __restrict__ xp)
{
    const int ip = blockIdx.x;
    const int t = threadIdx.x;
    const int bf = t >> 6, l = t & 63;
    const int b = (l & 15) + 16 * bf;
    const int i = 2 * ip + (l >= 32 ? 1 : 0);
    const int q0 = ((l >> 4) & 1) * 8;
    const float* xs = X + ((size_t)b * NI + i) * NQ + q0;
    const float4 u = *reinterpret_cast<const float4*>(xs);
    const float4 v = *reinterpret_cast<const float4*>(xs + 4);
    h8 h;
    h[0] = (_Float16)u.x; h[1] = (_Float16)u.y; h[2] = (_Float16)u.z; h[3] = (_Float16)u.w;
    h[4] = (_Float16)v.x; h[5] = (_Float16)v.y; h[6] = (_Float16)v.z; h[7] = (_Float16)v.w;
    xp[(size_t)(ip * 4 + bf) * 64 + l] = h;
}

// W pack, paired single-f16: wp[((j*NIP+ip)*2+pf)*64 + l] =
//   f16 W[j, 2ip+(l>=32), pf*16+(l&15), q0..q0+7]
__global__ __launch_bounds__(256)
void wpack_kernel(const float* __restrict__ Wg, h8* __restrict__ wp)
{
    const size_t g = (size_t)blockIdx.x * 256 + threadIdx.x;
    const int l = (int)(g & 63);
    const size_t rest = g >> 6;
    const int pf = (int)(rest & 1);
    const int ip = (int)((rest >> 1) & (NIP - 1));
    const int j  = (int)(rest >> 11);
    const int i = 2 * ip + (l >= 32 ? 1 : 0);
    const int p = pf * 16 + (l & 15);
    const int q0 = ((l >> 4) & 1) * 8;
    const float* src = Wg + (((size_t)j * NI + i) * NP + p) * NQ + q0;
    const float4 u = *reinterpret_cast<const float4*>(src);
    const float4 v = *reinterpret_cast<const float4*>(src + 4);
    h8 a;
    a[0] = (_Float16)u.x; a[1] = (_Float16)u.y; a[2] = (_Float16)u.z; a[3] = (_Float16)u.w;
    a[4] = (_Float16)v.x; a[5] = (_Float16)v.y; a[6] = (_Float16)v.z; a[7] = (_Float16)v.w;
    wp[g] = a;
}

__device__ inline float sqscale(float s2)
{
    return s2 / ((1.f + s2) * sqrtf(s2 + 1e-7f));
}

// K1: logits + softmax -> c (f16), squash fused:
//   SMODE 0: S = squash(U1/32) ;  SMODE 1: S = squash(U1/32) + squash(U2)
// block = i-chunk of 8 (4 ipairs), all 32 j, all 64 b; wave wv owns j=wv*4..+3.
template <int SMODE>
__global__ __launch_bounds__(512)
void logits_kernel(const h8* __restrict__ wp, const h8* __restrict__ xp,
                   const float* __restrict__ U1, const float* __restrict__ U2,
                   _Float16* __restrict__ cp)
{
    __shared__ float L[8][32][64];   // 64 KB logits (reused for c)
    const int t = threadIdx.x, wv = t >> 6, l = t & 63;
    const int i0 = blockIdx.x * 8;
    const bool lo = l >= 32;
    h8 zh;
#pragma unroll
    for (int e = 0; e < 8; ++e) zh[e] = (_Float16)0.f;

#pragma unroll 1
    for (int jj = 0; jj < 4; ++jj) {
        const int j = wv * 4 + jj;

        // ---- build S[b,j,p] fragments in-register (fused squash) ----
        float sreg[4][8];
#pragma unroll
        for (int bf = 0; bf < 4; ++bf) {
            const int b = (l & 15) + 16 * bf;
            const size_t base = ((size_t)b * NJ + j) * NP + (l >> 4) * 4;
            float va[8];
#pragma unroll
            for (int pf = 0; pf < 2; ++pf) {
                const f4 u = *reinterpret_cast<const f4*>(U1 + base + 16 * pf);
#pragma unroll
                for (int r = 0; r < 4; ++r) va[pf * 4 + r] = u[r] * (1.f / 32.f);
            }
            float s2 = 0.f;
#pragma unroll
            for (int e = 0; e < 8; ++e) s2 += va[e] * va[e];
            s2 += __shfl_xor(s2, 16);
            s2 += __shfl_xor(s2, 32);
            const float sc1 = sqscale(s2);
#pragma unroll
            for (int e = 0; e < 8; ++e) sreg[bf][e] = va[e] * sc1;

            if (SMODE == 1) {
                float vb[8];
#pragma unroll
                for (int pf = 0; pf < 2; ++pf) {
                    const f4 u = *reinterpret_cast<const f4*>(U2 + base + 16 * pf);
#pragma unroll
                    for (int r = 0; r < 4; ++r) vb[pf * 4 + r] = u[r];
                }
                float t2 = 0.f;
#pragma unroll
                for (int e = 0; e < 8; ++e) t2 += vb[e] * vb[e];
                t2 += __shfl_xor(t2, 16);
                t2 += __shfl_xor(t2, 32);
                const float sc2 = sqscale(t2);
#pragma unroll
                for (int e = 0; e < 8; ++e) sreg[bf][e] += vb[e] * sc2;
            }
        }

#pragma unroll 1
        for (int ipl = 0; ipl < 4; ++ipl) {
            const int ipg = blockIdx.x * 4 + ipl;
            const h8* wpji = wp + ((size_t)j * NIP + ipg) * 2 * 64 + l;
            const h8 A0 = wpji[0];
            const h8 A1 = wpji[64];
            const h8* xpb = xp + (size_t)ipg * 4 * 64 + l;
            h8 B[4];
#pragma unroll
            for (int bf = 0; bf < 4; ++bf) B[bf] = xpb[bf * 64];

            // ---- even i: zero the odd-half (lanes>=32) of B ----
#pragma unroll
            for (int half = 0; half < 2; ++half) {
                f4 D[2][4];
#pragma unroll
                for (int pf = 0; pf < 2; ++pf)
#pragma unroll
                    for (int bf = 0; bf < 4; ++bf) { f4 Z = {0.f, 0.f, 0.f, 0.f}; D[pf][bf] = Z; }
#pragma unroll
                for (int bf = 0; bf < 4; ++bf) {
                    const h8 Bm = ((half == 0) == lo) ? zh : B[bf];
                    D[0][bf] = __builtin_amdgcn_mfma_f32_16x16x32_f16(A0, Bm, D[0][bf], 0, 0, 0);
                    D[1][bf] = __builtin_amdgcn_mfma_f32_16x16x32_f16(A1, Bm, D[1][bf], 0, 0, 0);
                }
                // logit[b] = sum_p S[b,j,p] * hat[p,b]
                float part[4];
#pragma unroll
                for (int bf = 0; bf < 4; ++bf) {
                    float p_ = 0.f;
#pragma unroll
                    for (int pf = 0; pf < 2; ++pf)
#pragma unroll
                        for (int r = 0; r < 4; ++r) p_ += sreg[bf][pf * 4 + r] * D[pf][bf][r];
                    p_ += __shfl_xor(p_, 16);
                    p_ += __shfl_xor(p_, 32);
                    part[bf] = p_;
                }
                const int hb = l >> 4;
                const float wval = hb == 0 ? part[0] : hb == 1 ? part[1] : hb == 2 ? part[2] : part[3];
                L[ipl * 2 + half][j][(l & 15) + 16 * hb] = wval;
            }
        }
    }
    __syncthreads();

    // softmax over j, one thread per (b, ii); write c back into L
    {
        const int b = t & 63, ii = t >> 6;
        float lv[32];
        float m = -1e30f;
#pragma unroll
        for (int j = 0; j < 32; ++j) { lv[j] = L[ii][j][b]; m = fmaxf(m, lv[j]); }
        float s = 0.f;
#pragma unroll
        for (int j = 0; j < 32; ++j) { lv[j] = __expf(lv[j] - m); s += lv[j]; }
        const float inv = 1.f / s;
#pragma unroll
        for (int j = 0; j < 32; ++j) L[ii][j][b] = lv[j] * inv;
    }
    __syncthreads();

    // coalesced cp write: per (j,i) contiguous 128 B, pos r*4+e = c[b=16e+r]
    {
        const int jw = t >> 4, r = t & 15;
#pragma unroll 1
        for (int ii = 0; ii < 8; ++ii) {
            h4 c4;
#pragma unroll
            for (int e = 0; e < 4; ++e) c4[e] = (_Float16)L[ii][jw][16 * e + r];
            *reinterpret_cast<h4*>(cp + ((size_t)jw * NI + i0 + ii) * 64 + r * 4) = c4;
        }
    }
}

// K2: ACC[b,j,p] += sum_i c[b,j,i]*hat[b,j,i,p]  (HASC=false -> uniform c)
// block = (j, stripe of 64 ipairs); wave wv owns 8 ipairs, D-accumulated.
template <bool HASC>
__global__ __launch_bounds__(512)
void accum_kernel(const h8* __restrict__ wp, const h8* __restrict__ xp,
                  const _Float16* __restrict__ cp, float* __restrict__ ACC)
{
    const int t = threadIdx.x, wv = t >> 6, l = t & 63;
    const int j = blockIdx.x >> 4, is = blockIdx.x & 15;
    const bool lo = l >= 32;

    f4 D[2][4];
#pragma unroll
    for (int pf = 0; pf < 2; ++pf)
#pragma unroll
        for (int bf = 0; bf < 4; ++bf) { f4 Z = {0.f, 0.f, 0.f, 0.f}; D[pf][bf] = Z; }

    const int pbase = is * 64 + wv * 8;
#pragma unroll 1
    for (int ipl = 0; ipl < 8; ++ipl) {
        const int ipg = pbase + ipl;
        const h8* wpji = wp + ((size_t)j * NIP + ipg) * 2 * 64 + l;
        const h8 A0 = wpji[0];
        const h8 A1 = wpji[64];
        const h8* xpb = xp + (size_t)ipg * 4 * 64 + l;
        h4 c4;
        if (HASC) {
            const int i = 2 * ipg + (lo ? 1 : 0);
            c4 = *reinterpret_cast<const h4*>(cp + ((size_t)j * NI + i) * 64 + (l & 15) * 4);
        }
#pragma unroll
        for (int bf = 0; bf < 4; ++bf) {
            h8 B = xpb[bf * 64];
            if (HASC) B = B * c4[bf];   // per-lane c (lane's i-half)
            D[0][bf] = __builtin_amdgcn_mfma_f32_16x16x32_f16(A0, B, D[0][bf], 0, 0, 0);
            D[1][bf] = __builtin_amdgcn_mfma_f32_16x16x32_f16(A1, B, D[1][bf], 0, 0, 0);
        }
    }

    // cross-wave reduce in LDS, then one atomic per (b,p)
    __shared__ float R[8][64 * 36];
#pragma unroll
    for (int pf = 0; pf < 2; ++pf)
#pragma unroll
        for (int bf = 0; bf < 4; ++bf) {
            const int b = (l & 15) + 16 * bf, p = (l >> 4) * 4 + 16 * pf;
            *reinterpret_cast<f4*>(&R[wv][b * 36 + p]) = D[pf][bf];
        }
    __syncthreads();
#pragma unroll
    for (int k = 0; k < 4; ++k) {
        const int id = t + k * 512;
        const int b = id >> 5, p = id & 31;
        float s = 0.f;
#pragma unroll
        for (int w8 = 0; w8 < 8; ++w8) s += R[w8][b * 36 + p];
        atomicAdd(ACC + ((size_t)b * NJ + j) * NP + p, s);
    }
}

// out = squash(U) over last axis (P=32)
__global__ __launch_bounds__(256)
void squash_kernel(const float* __restrict__ U, float* __restrict__ OUT)
{
    const int t   = threadIdx.x;
    const int row = blockIdx.x * 8 + (t >> 5);
    const int p   = t & 31;
    const float val = U[row * 32 + p];
    float sq = val * val;
#pragma unroll
    for (int d = 1; d < 32; d <<= 1) sq += __shfl_xor(sq, d);
    OUT[row * 32 + p] = val * sqscale(sq);
}

extern "C" void kernel_launch(void* const* d_in, const int* in_sizes, int n_in,
                              void* d_out, int out_size, void* d_ws, size_t ws_size,
                              hipStream_t stream)
{
    const float* X  = (const float*)d_in[0];   // [64, 2048, 16]
    const float* Wg = (const float*)d_in[1];   // [32, 2048, 32, 16]
    float* out = (float*)d_out;                // [64, 32, 32]

    // ws: v1u,v2u,ou (768 KB, zeroed) | xp 4 MB | cp 8 MB | wp 64 MB
    float* v1u = (float*)d_ws;
    float* v2u = v1u + VSZ;
    float* ou  = v2u + VSZ;
    h8* xp = (h8*)((char*)d_ws + (size_t)3 * VSZ * 4);
    _Float16* cp = (_Float16*)((char*)xp + (size_t)NIP * 4 * 64 * 16);
    h8* wpk = (h8*)((char*)cp + (size_t)NJ * NI * 64 * 2);

    xpack_kernel<<<NIP, 256, 0, stream>>>(X, xp);
    wpack_kernel<<<(NJ * NIP * 2 * 64) / 256, 256, 0, stream>>>(Wg, wpk);
    zero_kernel<<<3 * VSZ * 4 / (256 * 16), 256, 0, stream>>>((f4*)d_ws);

    // pass A: c = 1/32 uniform -> v1u
    accum_kernel<false><<<512, 512, 0, stream>>>(wpk, xp, nullptr, v1u);

    // pass B: S = squash(v1u/32); logits+softmax -> cp; weighted accum -> v2u
    logits_kernel<0><<<NI / 8, 512, 0, stream>>>(wpk, xp, v1u, nullptr, cp);
    accum_kernel<true><<<512, 512, 0, stream>>>(wpk, xp, cp, v2u);

    // pass C: S = squash(v1u/32)+squash(v2u); logits -> cp; accum -> ou
    logits_kernel<1><<<NI / 8, 512, 0, stream>>>(wpk, xp, v1u, v2u, cp);
    accum_kernel<true><<<512, 512, 0, stream>>>(wpk, xp, cp, ou);

    squash_kernel<<<VSZ / 256, 256, 0, stream>>>(ou, out);
}

// Round 7
// 139.922 us; speedup vs baseline: 1.8015x; 1.0362x over previous
//
#include <hip/hip_runtime.h>

typedef _Float16 h8 __attribute__((ext_vector_type(8)));
typedef _Float16 h4 __attribute__((ext_vector_type(4)));
typedef float f4 __attribute__((ext_vector_type(4)));

constexpr int NB = 64;     // batch
constexpr int NI = 2048;   // input capsules
constexpr int NQ = 16;     // input dim
constexpr int NJ = 32;     // num capsules
constexpr int NP = 32;     // dim capsule
constexpr int NIP = NI / 2;         // 1024 i-pairs
constexpr int VSZ = NB * NJ * NP;   // 65536 per v-buffer

// ---------------------------------------------------------------------------
// MFMA plan (single-f16 W, i-PAIRED K):
//   per (j, ipair): D[p16,b16] += over K=32: k<16 -> W[j,i_e,p,q=k]*x[b,i_e,q]
//                                      k>=16 -> W[j,i_o,p,q=k-16]*x[b,i_o,q]
//   A lane layout: row p=l&15 (pf frag adds +16), i = l>=32 ? i_o : i_e,
//                  q0 = ((l>>4)&1)*8, elems e -> q0+e
//   B lane layout: col b=(l&15)+16bf, same (i, q) lane split as A
//   D lane layout: col b=l&15, row p=(l>>4)*4+reg (+16 per pf)
// wacc fuses W->f16 packing with the uniform-c pass-A accumulation.
// All ipl loops are software-pipelined: 1-ahead register prefetch under
// unroll 1 (explicit rotation; bounded VGPR pressure).
// ---------------------------------------------------------------------------

__global__ __launch_bounds__(256)
void zero_kernel(f4* __restrict__ p)
{
    const f4 z = {0.f, 0.f, 0.f, 0.f};
    p[(size_t)blockIdx.x * 256 + threadIdx.x] = z;
}

// x pack, paired: xp[(ip*4+bf)*64 + l] = x[b=(l&15)+16bf, i=2ip+(l>=32), q0..q0+7]
__global__ __launch_bounds__(256)
void xpack_kernel(const float* __restrict__ X, h8* __restrict__ xp)
{
    const int ip = blockIdx.x;
    const int t = threadIdx.x;
    const int bf = t >> 6, l = t & 63;
    const int b = (l & 15) + 16 * bf;
    const int i = 2 * ip + (l >= 32 ? 1 : 0);
    const int q0 = ((l >> 4) & 1) * 8;
    const float* xs = X + ((size_t)b * NI + i) * NQ + q0;
    const float4 u = *reinterpret_cast<const float4*>(xs);
    const float4 v = *reinterpret_cast<const float4*>(xs + 4);
    h8 h;
    h[0] = (_Float16)u.x; h[1] = (_Float16)u.y; h[2] = (_Float16)u.z; h[3] = (_Float16)u.w;
    h[4] = (_Float16)v.x; h[5] = (_Float16)v.y; h[6] = (_Float16)v.z; h[7] = (_Float16)v.w;
    xp[(size_t)(ip * 4 + bf) * 64 + l] = h;
}

__device__ inline float sqscale(float s2)
{
    return s2 / ((1.f + s2) * sqrtf(s2 + 1e-7f));
}

// K0: fused W pack + pass-A uniform accumulation.
// block = (j, stripe of 64 ipairs); wave wv owns 8 ipairs.
__global__ __launch_bounds__(512)
void wacc_kernel(const float* __restrict__ Wg, const h8* __restrict__ xp,
                 h8* __restrict__ wp, float* __restrict__ ACC)
{
    const int t = threadIdx.x, wv = t >> 6, l = t & 63;
    const int j = blockIdx.x >> 4, is = blockIdx.x & 15;
    const int ioff = (l >= 32) ? 1 : 0;
    const int q0 = ((l >> 4) & 1) * 8;
    const int pbase = is * 64 + wv * 8;

    f4 D[2][4];
#pragma unroll
    for (int pf = 0; pf < 2; ++pf)
#pragma unroll
        for (int bf = 0; bf < 4; ++bf) { f4 Z = {0.f, 0.f, 0.f, 0.f}; D[pf][bf] = Z; }

    // W f32 source for (ipg, pf): p = pf*16 + (l&15), i = 2*ipg + ioff
    const float* wgl = Wg + ((size_t)j * NI + ioff) * (NP * NQ) + (size_t)(l & 15) * NQ + q0;
    // per ipg step: 2*NP*NQ floats; frag1 offset: 16*NQ floats

    // prologue loads (ipl=0)
    f4 u0, u1, v0, v1;
    {
        const float* s0 = wgl + (size_t)(2 * pbase) * (NP * NQ);
        u0 = *reinterpret_cast<const f4*>(s0);
        u1 = *reinterpret_cast<const f4*>(s0 + 4);
        v0 = *reinterpret_cast<const f4*>(s0 + 16 * NQ);
        v1 = *reinterpret_cast<const f4*>(s0 + 16 * NQ + 4);
    }
    h8 B0, B1, B2, B3;
    {
        const h8* xpb = xp + (size_t)pbase * 4 * 64 + l;
        B0 = xpb[0]; B1 = xpb[64]; B2 = xpb[128]; B3 = xpb[192];
    }

#pragma unroll 1
    for (int ipl = 0; ipl < 8; ++ipl) {
        const int ipg = pbase + ipl;
        const int nip = (ipl < 7) ? ipg + 1 : ipg;
        // issue next-iter loads
        f4 nu0, nu1, nv0, nv1;
        {
            const float* s0 = wgl + (size_t)(2 * nip) * (NP * NQ);
            nu0 = *reinterpret_cast<const f4*>(s0);
            nu1 = *reinterpret_cast<const f4*>(s0 + 4);
            nv0 = *reinterpret_cast<const f4*>(s0 + 16 * NQ);
            nv1 = *reinterpret_cast<const f4*>(s0 + 16 * NQ + 4);
        }
        h8 nB0, nB1, nB2, nB3;
        {
            const h8* xpb = xp + (size_t)nip * 4 * 64 + l;
            nB0 = xpb[0]; nB1 = xpb[64]; nB2 = xpb[128]; nB3 = xpb[192];
        }

        // convert current W to f16 fragments
        h8 A0, A1;
#pragma unroll
        for (int e = 0; e < 4; ++e) {
            A0[e] = (_Float16)u0[e]; A0[e + 4] = (_Float16)u1[e];
            A1[e] = (_Float16)v0[e]; A1[e + 4] = (_Float16)v1[e];
        }
        // store packed W
        const size_t wo = ((size_t)j * NIP + ipg) * 2 * 64 + l;
        wp[wo] = A0;
        wp[wo + 64] = A1;
        // pass-A MFMA
        D[0][0] = __builtin_amdgcn_mfma_f32_16x16x32_f16(A0, B0, D[0][0], 0, 0, 0);
        D[1][0] = __builtin_amdgcn_mfma_f32_16x16x32_f16(A1, B0, D[1][0], 0, 0, 0);
        D[0][1] = __builtin_amdgcn_mfma_f32_16x16x32_f16(A0, B1, D[0][1], 0, 0, 0);
        D[1][1] = __builtin_amdgcn_mfma_f32_16x16x32_f16(A1, B1, D[1][1], 0, 0, 0);
        D[0][2] = __builtin_amdgcn_mfma_f32_16x16x32_f16(A0, B2, D[0][2], 0, 0, 0);
        D[1][2] = __builtin_amdgcn_mfma_f32_16x16x32_f16(A1, B2, D[1][2], 0, 0, 0);
        D[0][3] = __builtin_amdgcn_mfma_f32_16x16x32_f16(A0, B3, D[0][3], 0, 0, 0);
        D[1][3] = __builtin_amdgcn_mfma_f32_16x16x32_f16(A1, B3, D[1][3], 0, 0, 0);
        // rotate
        u0 = nu0; u1 = nu1; v0 = nv0; v1 = nv1;
        B0 = nB0; B1 = nB1; B2 = nB2; B3 = nB3;
    }

    // cross-wave reduce in LDS, then one atomic per (b,p)
    __shared__ float R[8][64 * 36];
#pragma unroll
    for (int pf = 0; pf < 2; ++pf)
#pragma unroll
        for (int bf = 0; bf < 4; ++bf) {
            const int b = (l & 15) + 16 * bf, p = (l >> 4) * 4 + 16 * pf;
            *reinterpret_cast<f4*>(&R[wv][b * 36 + p]) = D[pf][bf];
        }
    __syncthreads();
#pragma unroll
    for (int k = 0; k < 4; ++k) {
        const int id = t + k * 512;
        const int b = id >> 5, p = id & 31;
        float s = 0.f;
#pragma unroll
        for (int w8 = 0; w8 < 8; ++w8) s += R[w8][b * 36 + p];
        atomicAdd(ACC + ((size_t)b * NJ + j) * NP + p, s);
    }
}

// K1: logits + softmax -> c (f16), squash fused:
//   SMODE 0: S = squash(U1/32) ;  SMODE 1: S = squash(U1/32) + squash(U2)
// block = i-chunk of 8 (4 ipairs), all 32 j, all 64 b; wave wv owns j=wv*4..+3.
template <int SMODE>
__global__ __launch_bounds__(512)
void logits_kernel(const h8* __restrict__ wp, const h8* __restrict__ xp,
                   const float* __restrict__ U1, const float* __restrict__ U2,
                   _Float16* __restrict__ cp)
{
    __shared__ float L[8][32][64];   // 64 KB logits (reused for c)
    const int t = threadIdx.x, wv = t >> 6, l = t & 63;
    const int i0 = blockIdx.x * 8;
    const int ip0 = blockIdx.x * 4;
    const bool lo = l >= 32;
    h8 zh;
#pragma unroll
    for (int e = 0; e < 8; ++e) zh[e] = (_Float16)0.f;

#pragma unroll 1
    for (int jj = 0; jj < 4; ++jj) {
        const int j = wv * 4 + jj;

        // ---- build S[b,j,p] fragments in-register (fused squash) ----
        float sreg[4][8];
#pragma unroll
        for (int bf = 0; bf < 4; ++bf) {
            const int b = (l & 15) + 16 * bf;
            const size_t base = ((size_t)b * NJ + j) * NP + (l >> 4) * 4;
            float va[8];
#pragma unroll
            for (int pf = 0; pf < 2; ++pf) {
                const f4 u = *reinterpret_cast<const f4*>(U1 + base + 16 * pf);
#pragma unroll
                for (int r = 0; r < 4; ++r) va[pf * 4 + r] = u[r] * (1.f / 32.f);
            }
            float s2 = 0.f;
#pragma unroll
            for (int e = 0; e < 8; ++e) s2 += va[e] * va[e];
            s2 += __shfl_xor(s2, 16);
            s2 += __shfl_xor(s2, 32);
            const float sc1 = sqscale(s2);
#pragma unroll
            for (int e = 0; e < 8; ++e) sreg[bf][e] = va[e] * sc1;

            if (SMODE == 1) {
                float vb[8];
#pragma unroll
                for (int pf = 0; pf < 2; ++pf) {
                    const f4 u = *reinterpret_cast<const f4*>(U2 + base + 16 * pf);
#pragma unroll
                    for (int r = 0; r < 4; ++r) vb[pf * 4 + r] = u[r];
                }
                float t2 = 0.f;
#pragma unroll
                for (int e = 0; e < 8; ++e) t2 += vb[e] * vb[e];
                t2 += __shfl_xor(t2, 16);
                t2 += __shfl_xor(t2, 32);
                const float sc2 = sqscale(t2);
#pragma unroll
                for (int e = 0; e < 8; ++e) sreg[bf][e] += vb[e] * sc2;
            }
        }

        const h8* wj = wp + (size_t)j * NIP * 2 * 64 + l;
        // prologue A prefetch
        h8 A0 = wj[(size_t)ip0 * 128];
        h8 A1 = wj[(size_t)ip0 * 128 + 64];

#pragma unroll 1
        for (int ipl = 0; ipl < 4; ++ipl) {
            const int ipg = ip0 + ipl;
            const int nip = (ipl < 3) ? ipg + 1 : ipg;
            h8 nA0 = wj[(size_t)nip * 128];
            h8 nA1 = wj[(size_t)nip * 128 + 64];

            const h8* xpb = xp + (size_t)ipg * 4 * 64 + l;
            h8 B[4];
#pragma unroll
            for (int bf = 0; bf < 4; ++bf) B[bf] = xpb[bf * 64];

#pragma unroll
            for (int half = 0; half < 2; ++half) {
                f4 D[2][4];
#pragma unroll
                for (int pf = 0; pf < 2; ++pf)
#pragma unroll
                    for (int bf = 0; bf < 4; ++bf) { f4 Z = {0.f, 0.f, 0.f, 0.f}; D[pf][bf] = Z; }
#pragma unroll
                for (int bf = 0; bf < 4; ++bf) {
                    const h8 Bm = ((half == 0) == lo) ? zh : B[bf];
                    D[0][bf] = __builtin_amdgcn_mfma_f32_16x16x32_f16(A0, Bm, D[0][bf], 0, 0, 0);
                    D[1][bf] = __builtin_amdgcn_mfma_f32_16x16x32_f16(A1, Bm, D[1][bf], 0, 0, 0);
                }
                // logit[b] = sum_p S[b,j,p] * hat[p,b]
                float part[4];
#pragma unroll
                for (int bf = 0; bf < 4; ++bf) {
                    float p_ = 0.f;
#pragma unroll
                    for (int pf = 0; pf < 2; ++pf)
#pragma unroll
                        for (int r = 0; r < 4; ++r) p_ += sreg[bf][pf * 4 + r] * D[pf][bf][r];
                    p_ += __shfl_xor(p_, 16);
                    p_ += __shfl_xor(p_, 32);
                    part[bf] = p_;
                }
                const int hb = l >> 4;
                const float wval = hb == 0 ? part[0] : hb == 1 ? part[1] : hb == 2 ? part[2] : part[3];
                L[ipl * 2 + half][j][(l & 15) + 16 * hb] = wval;
            }
            A0 = nA0; A1 = nA1;
        }
    }
    __syncthreads();

    // softmax over j, one thread per (b, ii); write c back into L
    {
        const int b = t & 63, ii = t >> 6;
        float lv[32];
        float m = -1e30f;
#pragma unroll
        for (int j = 0; j < 32; ++j) { lv[j] = L[ii][j][b]; m = fmaxf(m, lv[j]); }
        float s = 0.f;
#pragma unroll
        for (int j = 0; j < 32; ++j) { lv[j] = __expf(lv[j] - m); s += lv[j]; }
        const float inv = 1.f / s;
#pragma unroll
        for (int j = 0; j < 32; ++j) L[ii][j][b] = lv[j] * inv;
    }
    __syncthreads();

    // coalesced cp write: per (j,i) contiguous 128 B, pos r*4+e = c[b=16e+r]
    {
        const int jw = t >> 4, r = t & 15;
#pragma unroll 1
        for (int ii = 0; ii < 8; ++ii) {
            h4 c4;
#pragma unroll
            for (int e = 0; e < 4; ++e) c4[e] = (_Float16)L[ii][jw][16 * e + r];
            *reinterpret_cast<h4*>(cp + ((size_t)jw * NI + i0 + ii) * 64 + r * 4) = c4;
        }
    }
}

// K2: ACC[b,j,p] += sum_i c[b,j,i]*hat[b,j,i,p]
// block = (j, stripe of 64 ipairs); wave wv owns 8 ipairs, D-accumulated.
__global__ __launch_bounds__(512)
void accum_kernel(const h8* __restrict__ wp, const h8* __restrict__ xp,
                  const _Float16* __restrict__ cp, float* __restrict__ ACC)
{
    const int t = threadIdx.x, wv = t >> 6, l = t & 63;
    const int j = blockIdx.x >> 4, is = blockIdx.x & 15;
    const int ioff = (l >= 32) ? 1 : 0;

    f4 D[2][4];
#pragma unroll
    for (int pf = 0; pf < 2; ++pf)
#pragma unroll
        for (int bf = 0; bf < 4; ++bf) { f4 Z = {0.f, 0.f, 0.f, 0.f}; D[pf][bf] = Z; }

    const int pbase = is * 64 + wv * 8;
    const h8* wj = wp + (size_t)j * NIP * 2 * 64 + l;
    const _Float16* cj = cp + ((size_t)j * NI + ioff) * 64 + (l & 15) * 4;

    // prologue prefetch (ipl=0)
    h8 A0 = wj[(size_t)pbase * 128];
    h8 A1 = wj[(size_t)pbase * 128 + 64];
    h8 B0, B1, B2, B3;
    {
        const h8* xpb = xp + (size_t)pbase * 4 * 64 + l;
        B0 = xpb[0]; B1 = xpb[64]; B2 = xpb[128]; B3 = xpb[192];
    }
    h4 c4 = *reinterpret_cast<const h4*>(cj + (size_t)(2 * pbase) * 64);

#pragma unroll 1
    for (int ipl = 0; ipl < 8; ++ipl) {
        const int ipg = pbase + ipl;
        const int nip = (ipl < 7) ? ipg + 1 : ipg;
        // issue next-iter loads
        h8 nA0 = wj[(size_t)nip * 128];
        h8 nA1 = wj[(size_t)nip * 128 + 64];
        h8 nB0, nB1, nB2, nB3;
        {
            const h8* xpb = xp + (size_t)nip * 4 * 64 + l;
            nB0 = xpb[0]; nB1 = xpb[64]; nB2 = xpb[128]; nB3 = xpb[192];
        }
        h4 nc4 = *reinterpret_cast<const h4*>(cj + (size_t)(2 * nip) * 64);

        // compute current
        h8 b0 = B0 * c4[0], b1 = B1 * c4[1], b2 = B2 * c4[2], b3 = B3 * c4[3];
        D[0][0] = __builtin_amdgcn_mfma_f32_16x16x32_f16(A0, b0, D[0][0], 0, 0, 0);
        D[1][0] = __builtin_amdgcn_mfma_f32_16x16x32_f16(A1, b0, D[1][0], 0, 0, 0);
        D[0][1] = __builtin_amdgcn_mfma_f32_16x16x32_f16(A0, b1, D[0][1], 0, 0, 0);
        D[1][1] = __builtin_amdgcn_mfma_f32_16x16x32_f16(A1, b1, D[1][1], 0, 0, 0);
        D[0][2] = __builtin_amdgcn_mfma_f32_16x16x32_f16(A0, b2, D[0][2], 0, 0, 0);
        D[1][2] = __builtin_amdgcn_mfma_f32_16x16x32_f16(A1, b2, D[1][2], 0, 0, 0);
        D[0][3] = __builtin_amdgcn_mfma_f32_16x16x32_f16(A0, b3, D[0][3], 0, 0, 0);
        D[1][3] = __builtin_amdgcn_mfma_f32_16x16x32_f16(A1, b3, D[1][3], 0, 0, 0);
        // rotate
        A0 = nA0; A1 = nA1; B0 = nB0; B1 = nB1; B2 = nB2; B3 = nB3; c4 = nc4;
    }

    // cross-wave reduce in LDS, then one atomic per (b,p)
    __shared__ float R[8][64 * 36];
#pragma unroll
    for (int pf = 0; pf < 2; ++pf)
#pragma unroll
        for (int bf = 0; bf < 4; ++bf) {
            const int b = (l & 15) + 16 * bf, p = (l >> 4) * 4 + 16 * pf;
            *reinterpret_cast<f4*>(&R[wv][b * 36 + p]) = D[pf][bf];
        }
    __syncthreads();
#pragma unroll
    for (int k = 0; k < 4; ++k) {
        const int id = t + k * 512;
        const int b = id >> 5, p = id & 31;
        float s = 0.f;
#pragma unroll
        for (int w8 = 0; w8 < 8; ++w8) s += R[w8][b * 36 + p];
        atomicAdd(ACC + ((size_t)b * NJ + j) * NP + p, s);
    }
}

// out = squash(U) over last axis (P=32)
__global__ __launch_bounds__(256)
void squash_kernel(const float* __restrict__ U, float* __restrict__ OUT)
{
    const int t   = threadIdx.x;
    const int row = blockIdx.x * 8 + (t >> 5);
    const int p   = t & 31;
    const float val = U[row * 32 + p];
    float sq = val * val;
#pragma unroll
    for (int d = 1; d < 32; d <<= 1) sq += __shfl_xor(sq, d);
    OUT[row * 32 + p] = val * sqscale(sq);
}

extern "C" void kernel_launch(void* const* d_in, const int* in_sizes, int n_in,
                              void* d_out, int out_size, void* d_ws, size_t ws_size,
                              hipStream_t stream)
{
    const float* X  = (const float*)d_in[0];   // [64, 2048, 16]
    const float* Wg = (const float*)d_in[1];   // [32, 2048, 32, 16]
    float* out = (float*)d_out;                // [64, 32, 32]

    // ws: v1u,v2u,ou (768 KB, zeroed) | xp 4 MB | cp 8 MB | wp 64 MB
    float* v1u = (float*)d_ws;
    float* v2u = v1u + VSZ;
    float* ou  = v2u + VSZ;
    h8* xp = (h8*)((char*)d_ws + (size_t)3 * VSZ * 4);
    _Float16* cp = (_Float16*)((char*)xp + (size_t)NIP * 4 * 64 * 16);
    h8* wpk = (h8*)((char*)cp + (size_t)NJ * NI * 64 * 2);

    xpack_kernel<<<NIP, 256, 0, stream>>>(X, xp);
    zero_kernel<<<3 * VSZ * 4 / (256 * 16), 256, 0, stream>>>((f4*)d_ws);

    // pass A fused with W packing: wp + v1u
    wacc_kernel<<<512, 512, 0, stream>>>(Wg, xp, wpk, v1u);

    // pass B: S = squash(v1u/32); logits+softmax -> cp; weighted accum -> v2u
    logits_kernel<0><<<NI / 8, 512, 0, stream>>>(wpk, xp, v1u, nullptr, cp);
    accum_kernel<<<512, 512, 0, stream>>>(wpk, xp, cp, v2u);

    // pass C: S = squash(v1u/32)+squash(v2u); logits -> cp; accum -> ou
    logits_kernel<1><<<NI / 8, 512, 0, stream>>>(wpk, xp, v1u, v2u, cp);
    accum_kernel<<<512, 512, 0, stream>>>(wpk, xp, cp, ou);

    squash_kernel<<<VSZ / 256, 256, 0, stream>>>(ou, out);
}